// Round 9
// baseline (248.686 us; speedup 1.0000x reference)
//
#include <hip/hip_runtime.h>
#include <math.h>

// Problem: B=16 rows, D=2^21 fp32 per row.
// loss = mean_i( sqrt( sum_j (out[i,j]-lab[i,j])^2 ) )
//
// R10: volatile-asm pipelining is ABANDONED - it killed the container 3/4
// attempts (R4/R8/R9), and its one surviving run (R5) had VGPR_Count=24,
// i.e. the rotating buffers were spilled to scratch and true MLP=8 was never
// actually on hardware. Best verified kernel: R7 (nt builtin loads, plain
// loop) = 246.8us bench, partial ~75us ~ 3.6 TB/s vs 6.9 TB/s fills in the
// same profile.
//
// This round raises MLP container-safely via T19 sched_group_barrier: a
// compile-time directive to the MachineScheduler (the pass that serialized
// every previous load batch - VGPR 24-32 each round) forcing emission order
// {8x VMEM_READ, 32x VALU} per batch. The waitcnt inserter then emits counted
// vmcnt automatically for the first consumer (~vmcnt(6)). No volatile asm,
// no forced live ranges: ~48 VGPR needed fits the 64-VGPR budget at 8
// waves/EU with no spill.
// Gate: VGPR_Count >= 48 proves the cluster reached the .s.
// If clustered and latency-bound: partial ~50-60us, bench ~220-230.
// If clustered and unchanged: dual-stream nt reads are service-limited at
// ~3.6 TB/s -> pattern roofline, declare next round.

constexpr int B = 16;
constexpr int D = 2097152;                         // 2^21 floats per row
constexpr int THREADS = 256;                       // 4 waves per block
constexpr int BLOCKS_PER_ROW = 128;
constexpr int GRID = B * BLOCKS_PER_ROW;           // 2048 = 256 CUs * 8 blocks
constexpr int F4_PER_ROW = D / 4;                  // 524288
constexpr int F4_PER_BLOCK = F4_PER_ROW / BLOCKS_PER_ROW;   // 4096
constexpr int BATCH = 4;                           // float4 per stream per batch
constexpr int F4_PER_BATCH = THREADS * BATCH;      // 1024
constexpr int NBATCH = F4_PER_BLOCK / F4_PER_BATCH;         // 4

using f32x4 = __attribute__((ext_vector_type(4))) float;

// LLVM SchedGroupMask (per guide T19 / m137): VALU=0x2, VMEM_READ=0x20
#define SGB(mask, n) __builtin_amdgcn_sched_group_barrier((mask), (n), 0)

__global__ __launch_bounds__(THREADS, 8)
void sqdiff_partial_kernel(const float4* __restrict__ out,
                           const float4* __restrict__ lab,
                           float* __restrict__ partials) {
    const int row   = blockIdx.x >> 7;             // / BLOCKS_PER_ROW
    const int chunk = blockIdx.x & (BLOCKS_PER_ROW - 1);
    const size_t blockbase = (size_t)row * F4_PER_ROW
                           + (size_t)chunk * F4_PER_BLOCK;

    const f32x4* op = reinterpret_cast<const f32x4*>(out);
    const f32x4* lp = reinterpret_cast<const f32x4*>(lab);

    float a0 = 0.0f, a1 = 0.0f, a2 = 0.0f, a3 = 0.0f;

#pragma unroll 1
    for (int b = 0; b < NBATCH; ++b) {
        const size_t idx = blockbase + (size_t)b * F4_PER_BATCH + threadIdx.x;

        f32x4 o[BATCH], l[BATCH];
        // Interleave o,l per i so the first consumer (pair 0) is the two
        // OLDEST loads -> compiler's waitcnt inserter emits vmcnt(6).
#pragma unroll
        for (int i = 0; i < BATCH; ++i) {
            o[i] = __builtin_nontemporal_load(op + idx + (size_t)i * THREADS);
            l[i] = __builtin_nontemporal_load(lp + idx + (size_t)i * THREADS);
        }

#pragma unroll
        for (int i = 0; i < BATCH; ++i) {
            const float dx = o[i][0] - l[i][0];
            const float dy = o[i][1] - l[i][1];
            const float dz = o[i][2] - l[i][2];
            const float dw = o[i][3] - l[i][3];
            a0 = fmaf(dx, dx, a0);                 // 4 independent chains
            a1 = fmaf(dy, dy, a1);
            a2 = fmaf(dz, dz, a2);
            a3 = fmaf(dw, dw, a3);
        }

        // Pin the emission order for this scheduling region:
        // all 8 loads first, then the 32-op VALU block (16 sub + 16 fma).
        SGB(0x20, 8);     // 8x VMEM_READ
        SGB(0x02, 32);    // 32x VALU
    }

    float acc = (a0 + a1) + (a2 + a3);

    // wave-64 tree reduce
#pragma unroll
    for (int off = 32; off > 0; off >>= 1)
        acc += __shfl_down(acc, off, 64);

    __shared__ float smem[THREADS / 64];
    const int lane = threadIdx.x & 63;
    const int wave = threadIdx.x >> 6;
    if (lane == 0) smem[wave] = acc;
    __syncthreads();

    if (threadIdx.x == 0) {
        // plain store, no atomic: partials laid out [row][chunk] == blockIdx.x
        partials[blockIdx.x] = smem[0] + smem[1] + smem[2] + smem[3];
    }
}

// One block, 1024 threads = 16 waves. Wave w reduces row w's 128 partials.
__global__ __launch_bounds__(1024)
void finalize_kernel(const float* __restrict__ partials,
                     float* __restrict__ loss) {
    const int wave = threadIdx.x >> 6;   // 0..15 == row
    const int lane = threadIdx.x & 63;

    float s = partials[wave * BLOCKS_PER_ROW + lane]
            + partials[wave * BLOCKS_PER_ROW + 64 + lane];

#pragma unroll
    for (int off = 32; off > 0; off >>= 1)
        s += __shfl_down(s, off, 64);

    __shared__ float row_dist[B];
    if (lane == 0) row_dist[wave] = sqrtf(s);
    __syncthreads();

    if (wave == 0) {
        float v = (lane < B) ? row_dist[lane] : 0.0f;
#pragma unroll
        for (int off = 32; off > 0; off >>= 1)
            v += __shfl_down(v, off, 64);
        if (lane == 0) loss[0] = v * (1.0f / (float)B);
    }
}

extern "C" void kernel_launch(void* const* d_in, const int* in_sizes, int n_in,
                              void* d_out, int out_size, void* d_ws, size_t ws_size,
                              hipStream_t stream) {
    const float4* out_p = (const float4*)d_in[0];
    const float4* lab_p = (const float4*)d_in[1];
    float* partials = (float*)d_ws;      // 2048 floats of scratch, fully overwritten

    sqdiff_partial_kernel<<<GRID, THREADS, 0, stream>>>(out_p, lab_p, partials);
    finalize_kernel<<<1, 1024, 0, stream>>>(partials, (float*)d_out);
}